// Round 7
// baseline (395.387 us; speedup 1.0000x reference)
//
#include <hip/hip_runtime.h>
#include <hip/hip_bf16.h>
#include <math.h>

#define E_EXPERTS 8
#define D_DIM 768
#define H_DIM 3072
#define N_TOK 8192          // B*T = 4*2048
#define SLOTS (2 * N_TOK)
#define SCAT_BLOCKS 32      // hist/scatter blocks (256 tokens each)
#define MB_L 20             // launched m-blocks per group (covers ne <= 2560)

typedef unsigned short ushort_t;
typedef __attribute__((ext_vector_type(8))) __bf16 bf16x8;
typedef __attribute__((ext_vector_type(4))) float f32x4;

__device__ __forceinline__ unsigned short f2bf(float f) {
    unsigned int u = __float_as_uint(f);
    unsigned int r = (u + 0x7FFFu + ((u >> 16) & 1u)) >> 16;
    return (unsigned short)r;
}

// async 16B global -> LDS (wave-uniform LDS base + lane*16; global addr per-lane)
__device__ __forceinline__ void gload_lds16(const void* g, void* l) {
    __builtin_amdgcn_global_load_lds(
        (const __attribute__((address_space(1))) unsigned int*)g,
        (__attribute__((address_space(3))) unsigned int*)l, 16, 0, 0);
}

// ---------------- prep kernels ----------------

// dst[e][c][r] = bf16(src[e][r][c]);  R,C multiples of 64
__global__ void transpose_conv_kernel(const float* __restrict__ src, ushort_t* __restrict__ dst,
                                      int R, int C) {
    __shared__ float tile[64][65];
    int e = blockIdx.z;
    const float* S = src + (size_t)e * R * C;
    ushort_t* Dp = dst + (size_t)e * R * C;
    int c0 = blockIdx.x * 64, r0 = blockIdx.y * 64;
    int tx = threadIdx.x & 15, ty = threadIdx.x >> 4;  // 16 x 16
#pragma unroll
    for (int p = 0; p < 4; p++) {
        float4 v = *(const float4*)&S[(size_t)(r0 + ty + 16 * p) * C + c0 + tx * 4];
        tile[ty + 16 * p][tx * 4 + 0] = v.x;
        tile[ty + 16 * p][tx * 4 + 1] = v.y;
        tile[ty + 16 * p][tx * 4 + 2] = v.z;
        tile[ty + 16 * p][tx * 4 + 3] = v.w;
    }
    __syncthreads();
#pragma unroll
    for (int p = 0; p < 4; p++) {
        int cc = ty + 16 * p;
        int rr = tx * 4;
        ushort4 o;
        o.x = f2bf(tile[rr + 0][cc]);
        o.y = f2bf(tile[rr + 1][cc]);
        o.z = f2bf(tile[rr + 2][cc]);
        o.w = f2bf(tile[rr + 3][cc]);
        *(ushort4*)&Dp[(size_t)(c0 + cc) * R + r0 + rr] = o;
    }
}

// ---------------- routing ----------------

__global__ void gate_kernel(const float* __restrict__ x, const float* __restrict__ Wg,
                            const float* __restrict__ bg, ushort_t* __restrict__ xb,
                            int* __restrict__ top_idx, float* __restrict__ top_w) {
    int w = threadIdx.x >> 6, lane = threadIdx.x & 63;
    int t = blockIdx.x * 4 + w;
    if (t >= N_TOK) return;
    const float* xr = x + (size_t)t * D_DIM;
    float xs[12];
#pragma unroll
    for (int j = 0; j < 12; j++) xs[j] = xr[lane + 64 * j];
#pragma unroll
    for (int j = 0; j < 12; j++) xb[(size_t)t * D_DIM + lane + 64 * j] = f2bf(xs[j]);
    float pr[8];
#pragma unroll
    for (int ee = 0; ee < 8; ee++) {
        const float* wr = Wg + ee * D_DIM;
        float p = 0.f;
#pragma unroll
        for (int j = 0; j < 12; j++) p += xs[j] * wr[lane + 64 * j];
#pragma unroll
        for (int o = 32; o > 0; o >>= 1) p += __shfl_xor(p, o);
        pr[ee] = p + bg[ee];
    }
    float mx = pr[0];
#pragma unroll
    for (int ee = 1; ee < 8; ee++) mx = fmaxf(mx, pr[ee]);
    float s = 0.f;
#pragma unroll
    for (int ee = 0; ee < 8; ee++) { pr[ee] = expf(pr[ee] - mx); s += pr[ee]; }
    float inv = 1.f / s;
#pragma unroll
    for (int ee = 0; ee < 8; ee++) pr[ee] *= inv;
    int i0 = 0;
#pragma unroll
    for (int ee = 1; ee < 8; ee++) if (pr[ee] > pr[i0]) i0 = ee;
    int i1 = -1;
#pragma unroll
    for (int ee = 0; ee < 8; ee++) {
        if (ee == i0) continue;
        if (i1 < 0 || pr[ee] > pr[i1]) i1 = ee;
    }
    if (lane == 0) {
        top_idx[2 * t] = i0;
        top_idx[2 * t + 1] = i1;
        top_w[2 * t] = pr[i0];
        top_w[2 * t + 1] = pr[i1];
    }
}

__global__ void hist_kernel(const int* __restrict__ top_idx, int* __restrict__ bc) {
    __shared__ int h[E_EXPERTS];
    if (threadIdx.x < E_EXPERTS) h[threadIdx.x] = 0;
    __syncthreads();
    int t = blockIdx.x * 256 + threadIdx.x;
    atomicAdd(&h[top_idx[2 * t]], 1);
    atomicAdd(&h[top_idx[2 * t + 1]], 1);
    __syncthreads();
    if (threadIdx.x < E_EXPERTS) bc[blockIdx.x * E_EXPERTS + threadIdx.x] = h[threadIdx.x];
}

__global__ void scan_kernel(const int* __restrict__ bc, int* __restrict__ counts,
                            int* __restrict__ offsets, int* __restrict__ base) {
    int tid = threadIdx.x;
    if (tid < E_EXPERTS) {
        int acc = 0;
        for (int b = 0; b < SCAT_BLOCKS; b++) {
            base[b * E_EXPERTS + tid] = acc;
            acc += bc[b * E_EXPERTS + tid];
        }
        counts[tid] = acc;
    }
    __syncthreads();
    if (tid == 0) {
        int acc = 0;
        for (int e = 0; e < E_EXPERTS; e++) { offsets[e] = acc; acc += counts[e]; }
    }
    __syncthreads();
    if (tid < E_EXPERTS) {
        int o = offsets[tid];
        for (int b = 0; b < SCAT_BLOCKS; b++) base[b * E_EXPERTS + tid] += o;
    }
}

__global__ void scatter_kernel(const int* __restrict__ top_idx, const float* __restrict__ top_w,
                               const int* __restrict__ base, int* __restrict__ perm,
                               float* __restrict__ wgt, int* __restrict__ tok2slot) {
    __shared__ int cur[E_EXPERTS];
    if (threadIdx.x < E_EXPERTS) cur[threadIdx.x] = 0;
    __syncthreads();
    int t = blockIdx.x * 256 + threadIdx.x;
#pragma unroll
    for (int sl = 0; sl < 2; sl++) {
        int ee = top_idx[2 * t + sl];
        int p = atomicAdd(&cur[ee], 1);
        int s = base[blockIdx.x * E_EXPERTS + ee] + p;
        perm[s] = t;
        wgt[s] = top_w[2 * t + sl];
        tok2slot[2 * t + sl] = s;
    }
}

// combine: out[t][d] = y[s0][d] + y[s1][d]
__global__ void combine_kernel(const float* __restrict__ y, const int* __restrict__ tok2slot,
                               float* __restrict__ out) {
    int idx = blockIdx.x * blockDim.x + threadIdx.x;
    int stride = gridDim.x * blockDim.x;
    const int QR = D_DIM / 4;  // float4 per row
    for (int i = idx; i < N_TOK * QR; i += stride) {
        int t = i / QR, d4 = i - t * QR;
        int s0 = tok2slot[2 * t], s1 = tok2slot[2 * t + 1];
        float4 a = ((const float4*)(y + (size_t)s0 * D_DIM))[d4];
        float4 b = ((const float4*)(y + (size_t)s1 * D_DIM))[d4];
        float4 o;
        o.x = a.x + b.x; o.y = a.y + b.y; o.z = a.z + b.z; o.w = a.w + b.w;
        ((float4*)(out + (size_t)t * D_DIM))[d4] = o;
    }
}

// ------- expert GEMMs: 128x128, BK=32, TRI-buffered, 1 barrier per K-tile (T2+T4+T5) -------
// 256 threads = 4 waves (2M x 2N); 48 KiB LDS -> 3 blocks/CU (3-way stall cross-coverage, m114).
// Tri-buffer: stage(t+2) targets buf (t+2)%3 which is never concurrently read/written ->
// first phase barrier removable. Per K-tile: stage 4 gloads; read 8 ds_read_b128; lgkm; 16 MFMA;
// vmcnt(4) (t+1 drained, t+2 in flight; never 0 mid-loop); s_barrier.
// BK=32 swizzle (both-sides, rule 21): row r granule g stored at phys pg=(g+(r>>1))&3;
// source pre-applies inverse, frag reads apply same map -> uniform 8 lanes/16B-slot (b128 optimum).
// 1-D XCD-grouped grid: wgid = c + 8*(mb + MB_L*q); g = q*8+c -> (e = g/NB, nb = g%NB).
// MODE 0: A = xb gathered via perm, B = W1T[e], epilogue GELU -> Hout bf16
// MODE 1: A = Hb contiguous,  B = W2T[e], epilogue weighted+bias -> Y f32 (no atomics)
template <int MODE>
__global__ __launch_bounds__(256, 3) void moe_gemm_kernel(
    const ushort_t* __restrict__ A, const ushort_t* __restrict__ BT,
    const float* __restrict__ bias, const int* __restrict__ offsets,
    const int* __restrict__ counts, const int* __restrict__ perm,
    const float* __restrict__ wgt, ushort_t* __restrict__ Hout, float* __restrict__ Y) {
    constexpr int K = (MODE == 0) ? D_DIM : H_DIM;
    constexpr int N = (MODE == 0) ? H_DIM : D_DIM;
    constexpr int KT = K / 32;
    constexpr int NB = N / 128;

    const int wgid = blockIdx.x;
    const int c = wgid & 7;
    const int r = wgid >> 3;
    const int mb = r % MB_L;
    const int q = r / MB_L;
    const int g = q * 8 + c;
    const int e = g / NB;
    const int nb = g % NB;

    const int ne = counts[e];
    const int m0 = mb * 128;
    if (m0 >= ne) return;
    const int n0 = nb * 128;
    const int base = offsets[e];
    const ushort_t* Bt = BT + (size_t)e * ((size_t)N * K);

    __shared__ alignas(16) ushort_t As[3 * 128 * 32];
    __shared__ alignas(16) ushort_t Bs[3 * 128 * 32];

    const int tid = threadIdx.x;
    const int lane = tid & 63;
    const int w = tid >> 6;
    const int wm = w >> 1, wn = w & 1;           // 2 x 2 wave grid
    const int lr = lane & 15;
    const int gq = lane >> 4;                    // k-granule 0..3 (8 bf16 each)

    // staging: wave w covers segments {2w, 2w+1}; seg s = 16 rows (1 KB).
    // lane l: row = s*16 + (l>>2), phys granule pg = l&3; logical lg = (pg - (row>>1)) & 3
    int lds_dst[2];        // element offset within a buffer (wave-uniform)
    int a_src[2], b_src[2];
#pragma unroll
    for (int i = 0; i < 2; i++) {
        int s = 2 * w + i;
        int row = s * 16 + (lane >> 2);
        int lg = ((lane & 3) - (row >> 1)) & 3;
        int rcl = min(m0 + row, ne - 1);
        int arow = (MODE == 0) ? perm[base + rcl] : (base + rcl);
        a_src[i] = arow * K + lg * 8;
        b_src[i] = (n0 + row) * K + lg * 8;
        lds_dst[i] = s * 512;
    }

    auto stage = [&](int tt, int bi) {
#pragma unroll
        for (int i = 0; i < 2; i++) {
            gload_lds16(A + (size_t)a_src[i] + (size_t)tt * 32, &As[bi * 4096 + lds_dst[i]]);
            gload_lds16(Bt + (size_t)b_src[i] + (size_t)tt * 32, &Bs[bi * 4096 + lds_dst[i]]);
        }
    };

    f32x4 acc[4][4];
#pragma unroll
    for (int i = 0; i < 4; i++)
#pragma unroll
        for (int j = 0; j < 4; j++) acc[i][j] = (f32x4){0.f, 0.f, 0.f, 0.f};

    // prologue: stage t=0 and t=1; wait t=0 (4 loads of t=1 stay in flight)
    stage(0, 0);
    stage(1, 1);
    asm volatile("s_waitcnt vmcnt(4)" ::: "memory");
    __builtin_amdgcn_s_barrier();

    int cur = 0;
    for (int t = 0; t < KT; ++t) {
        // issue prefetch of t+2 into the free buffer (never conflicts: tri-buffer)
        int sb = cur + 2; if (sb >= 3) sb -= 3;
        if (t + 2 < KT) stage(t + 2, sb);
        // fragment reads from buf cur (swizzled: phys granule = (gq + (R>>1)) & 3)
        bf16x8 af[4], bfr[4];
#pragma unroll
        for (int f = 0; f < 4; f++) {
            int Ra = wm * 64 + f * 16 + lr;
            int Rb = wn * 64 + f * 16 + lr;
            af[f]  = *(const bf16x8*)&As[cur * 4096 + Ra * 32 + (((gq + (Ra >> 1)) & 3) << 3)];
            bfr[f] = *(const bf16x8*)&Bs[cur * 4096 + Rb * 32 + (((gq + (Rb >> 1)) & 3) << 3)];
        }
        asm volatile("s_waitcnt lgkmcnt(0)" ::: "memory");
        __builtin_amdgcn_s_setprio(1);
#pragma unroll
        for (int fm = 0; fm < 4; fm++)
#pragma unroll
            for (int fc = 0; fc < 4; fc++)
                acc[fm][fc] = __builtin_amdgcn_mfma_f32_16x16x32_bf16(
                    af[fm], bfr[fc], acc[fm][fc], 0, 0, 0);
        __builtin_amdgcn_s_setprio(0);
        // drain t+1's staging (keep t+2's 4 loads in flight); all-waves barrier makes it visible
        if (t + 2 < KT) asm volatile("s_waitcnt vmcnt(4)" ::: "memory");
        else            asm volatile("s_waitcnt vmcnt(0)" ::: "memory");
        __builtin_amdgcn_s_barrier();
        cur = (cur == 2) ? 0 : cur + 1;
    }

    const int rg0 = gq * 4;
#pragma unroll
    for (int fr = 0; fr < 4; fr++) {
#pragma unroll
        for (int fc = 0; fc < 4; fc++) {
            int cn = n0 + wn * 64 + fc * 16 + lr;
            float bi = bias[e * N + cn];
            f32x4 v = acc[fr][fc];
#pragma unroll
            for (int rg = 0; rg < 4; rg++) {
                int rm = m0 + wm * 64 + fr * 16 + rg0 + rg;
                if (rm < ne) {
                    if (MODE == 0) {
                        float xv = v[rg] + bi;
                        // gelu(x) ~= x * sigmoid(2*0.7978845608*(x + 0.044715 x^3))
                        float u = xv * 1.5957691216f * __builtin_fmaf(0.044715f * xv, xv, 1.0f);
                        float gl = xv / (1.f + __expf(-u));
                        Hout[(size_t)(base + rm) * H_DIM + cn] = f2bf(gl);
                    } else {
                        int s = base + rm;
                        float wv = wgt[s];
                        Y[(size_t)s * D_DIM + cn] = wv * (v[rg] + bi);
                    }
                }
            }
        }
    }
}

// ---------------- launch ----------------

extern "C" void kernel_launch(void* const* d_in, const int* in_sizes, int n_in,
                              void* d_out, int out_size, void* d_ws, size_t ws_size,
                              hipStream_t stream) {
    const float* x  = (const float*)d_in[0];
    const float* Wg = (const float*)d_in[1];
    const float* bg = (const float*)d_in[2];
    const float* W1 = (const float*)d_in[3];
    const float* b1 = (const float*)d_in[4];
    const float* W2 = (const float*)d_in[5];
    const float* b2 = (const float*)d_in[6];
    float* out = (float*)d_out;

    char* p = (char*)d_ws;
    ushort_t* xb  = (ushort_t*)p; p += (size_t)N_TOK * D_DIM * 2;
    ushort_t* W1T = (ushort_t*)p; p += (size_t)E_EXPERTS * H_DIM * D_DIM * 2;
    ushort_t* W2T = (ushort_t*)p; p += (size_t)E_EXPERTS * D_DIM * H_DIM * 2;
    ushort_t* Hb  = (ushort_t*)p; p += (size_t)SLOTS * H_DIM * 2;
    int*   top_idx = (int*)p;   p += (size_t)N_TOK * 2 * 4;
    float* top_w   = (float*)p; p += (size_t)N_TOK * 2 * 4;
    int*   perm    = (int*)p;   p += (size_t)SLOTS * 4;
    float* wgt     = (float*)p; p += (size_t)SLOTS * 4;
    int*   t2s     = (int*)p;   p += (size_t)SLOTS * 4;
    int*   bc      = (int*)p;   p += SCAT_BLOCKS * E_EXPERTS * 4;
    int*   basep   = (int*)p;   p += SCAT_BLOCKS * E_EXPERTS * 4;
    int*   counts  = (int*)p;   p += 64;
    int*   offsets = (int*)p;   p += 64;
    // y aliases xb+W1T (dead by GEMM2): 50.3 MB < 62.9 MB
    float* y = (float*)d_ws;

    gate_kernel<<<N_TOK / 4, 256, 0, stream>>>(x, Wg, bg, xb, top_idx, top_w);
    transpose_conv_kernel<<<dim3(H_DIM / 64, D_DIM / 64, E_EXPERTS), 256, 0, stream>>>(W1, W1T, D_DIM, H_DIM);
    transpose_conv_kernel<<<dim3(D_DIM / 64, H_DIM / 64, E_EXPERTS), 256, 0, stream>>>(W2, W2T, H_DIM, D_DIM);
    hist_kernel<<<SCAT_BLOCKS, 256, 0, stream>>>(top_idx, bc);
    scan_kernel<<<1, 64, 0, stream>>>(bc, counts, offsets, basep);
    scatter_kernel<<<SCAT_BLOCKS, 256, 0, stream>>>(top_idx, top_w, basep, perm, wgt, t2s);
    moe_gemm_kernel<0><<<8 * MB_L * (H_DIM / 128), 256, 0, stream>>>(
        xb, W1T, b1, offsets, counts, perm, wgt, Hb, nullptr);
    moe_gemm_kernel<1><<<8 * MB_L * (D_DIM / 128), 256, 0, stream>>>(
        Hb, W2T, b2, offsets, counts, perm, wgt, nullptr, y);
    combine_kernel<<<2048, 256, 0, stream>>>(y, t2s, out);
}

// Round 9
// 378.746 us; speedup vs baseline: 1.0439x; 1.0439x over previous
//
#include <hip/hip_runtime.h>
#include <hip/hip_bf16.h>
#include <math.h>

#define E_EXPERTS 8
#define D_DIM 768
#define H_DIM 3072
#define N_TOK 8192          // B*T = 4*2048
#define SLOTS (2 * N_TOK)
#define SCAT_BLOCKS 32      // hist/scatter blocks (256 tokens each)
#define MB_L 20             // launched m-blocks per group (covers ne <= 2560)

typedef unsigned short ushort_t;
typedef __attribute__((ext_vector_type(8))) __bf16 bf16x8;
typedef __attribute__((ext_vector_type(4))) float f32x4;

__device__ __forceinline__ unsigned short f2bf(float f) {
    unsigned int u = __float_as_uint(f);
    unsigned int r = (u + 0x7FFFu + ((u >> 16) & 1u)) >> 16;
    return (unsigned short)r;
}

// async 16B global -> LDS (wave-uniform LDS base + lane*16; global addr per-lane)
__device__ __forceinline__ void gload_lds16(const void* g, void* l) {
    __builtin_amdgcn_global_load_lds(
        (const __attribute__((address_space(1))) unsigned int*)g,
        (__attribute__((address_space(3))) unsigned int*)l, 16, 0, 0);
}

// ---------------- prep kernels ----------------

// dst[e][c][r] = bf16(src[e][r][c]);  R,C multiples of 64
__global__ void transpose_conv_kernel(const float* __restrict__ src, ushort_t* __restrict__ dst,
                                      int R, int C) {
    __shared__ float tile[64][65];
    int e = blockIdx.z;
    const float* S = src + (size_t)e * R * C;
    ushort_t* Dp = dst + (size_t)e * R * C;
    int c0 = blockIdx.x * 64, r0 = blockIdx.y * 64;
    int tx = threadIdx.x & 15, ty = threadIdx.x >> 4;  // 16 x 16
#pragma unroll
    for (int p = 0; p < 4; p++) {
        float4 v = *(const float4*)&S[(size_t)(r0 + ty + 16 * p) * C + c0 + tx * 4];
        tile[ty + 16 * p][tx * 4 + 0] = v.x;
        tile[ty + 16 * p][tx * 4 + 1] = v.y;
        tile[ty + 16 * p][tx * 4 + 2] = v.z;
        tile[ty + 16 * p][tx * 4 + 3] = v.w;
    }
    __syncthreads();
#pragma unroll
    for (int p = 0; p < 4; p++) {
        int cc = ty + 16 * p;
        int rr = tx * 4;
        ushort4 o;
        o.x = f2bf(tile[rr + 0][cc]);
        o.y = f2bf(tile[rr + 1][cc]);
        o.z = f2bf(tile[rr + 2][cc]);
        o.w = f2bf(tile[rr + 3][cc]);
        *(ushort4*)&Dp[(size_t)(c0 + cc) * R + r0 + rr] = o;
    }
}

// ---------------- routing ----------------

__global__ void gate_kernel(const float* __restrict__ x, const float* __restrict__ Wg,
                            const float* __restrict__ bg, ushort_t* __restrict__ xb,
                            int* __restrict__ top_idx, float* __restrict__ top_w) {
    int w = threadIdx.x >> 6, lane = threadIdx.x & 63;
    int t = blockIdx.x * 4 + w;
    if (t >= N_TOK) return;
    const float* xr = x + (size_t)t * D_DIM;
    float xs[12];
#pragma unroll
    for (int j = 0; j < 12; j++) xs[j] = xr[lane + 64 * j];
#pragma unroll
    for (int j = 0; j < 12; j++) xb[(size_t)t * D_DIM + lane + 64 * j] = f2bf(xs[j]);
    float pr[8];
#pragma unroll
    for (int ee = 0; ee < 8; ee++) {
        const float* wr = Wg + ee * D_DIM;
        float p = 0.f;
#pragma unroll
        for (int j = 0; j < 12; j++) p += xs[j] * wr[lane + 64 * j];
#pragma unroll
        for (int o = 32; o > 0; o >>= 1) p += __shfl_xor(p, o);
        pr[ee] = p + bg[ee];
    }
    float mx = pr[0];
#pragma unroll
    for (int ee = 1; ee < 8; ee++) mx = fmaxf(mx, pr[ee]);
    float s = 0.f;
#pragma unroll
    for (int ee = 0; ee < 8; ee++) { pr[ee] = expf(pr[ee] - mx); s += pr[ee]; }
    float inv = 1.f / s;
#pragma unroll
    for (int ee = 0; ee < 8; ee++) pr[ee] *= inv;
    int i0 = 0;
#pragma unroll
    for (int ee = 1; ee < 8; ee++) if (pr[ee] > pr[i0]) i0 = ee;
    int i1 = -1;
#pragma unroll
    for (int ee = 0; ee < 8; ee++) {
        if (ee == i0) continue;
        if (i1 < 0 || pr[ee] > pr[i1]) i1 = ee;
    }
    if (lane == 0) {
        top_idx[2 * t] = i0;
        top_idx[2 * t + 1] = i1;
        top_w[2 * t] = pr[i0];
        top_w[2 * t + 1] = pr[i1];
    }
}

__global__ void hist_kernel(const int* __restrict__ top_idx, int* __restrict__ bc) {
    __shared__ int h[E_EXPERTS];
    if (threadIdx.x < E_EXPERTS) h[threadIdx.x] = 0;
    __syncthreads();
    int t = blockIdx.x * 256 + threadIdx.x;
    atomicAdd(&h[top_idx[2 * t]], 1);
    atomicAdd(&h[top_idx[2 * t + 1]], 1);
    __syncthreads();
    if (threadIdx.x < E_EXPERTS) bc[blockIdx.x * E_EXPERTS + threadIdx.x] = h[threadIdx.x];
}

__global__ void scan_kernel(const int* __restrict__ bc, int* __restrict__ counts,
                            int* __restrict__ offsets, int* __restrict__ base) {
    int tid = threadIdx.x;
    if (tid < E_EXPERTS) {
        int acc = 0;
        for (int b = 0; b < SCAT_BLOCKS; b++) {
            base[b * E_EXPERTS + tid] = acc;
            acc += bc[b * E_EXPERTS + tid];
        }
        counts[tid] = acc;
    }
    __syncthreads();
    if (tid == 0) {
        int acc = 0;
        for (int e = 0; e < E_EXPERTS; e++) { offsets[e] = acc; acc += counts[e]; }
    }
    __syncthreads();
    if (tid < E_EXPERTS) {
        int o = offsets[tid];
        for (int b = 0; b < SCAT_BLOCKS; b++) base[b * E_EXPERTS + tid] += o;
    }
}

__global__ void scatter_kernel(const int* __restrict__ top_idx, const float* __restrict__ top_w,
                               const int* __restrict__ base, int* __restrict__ perm,
                               float* __restrict__ wgt, int* __restrict__ tok2slot) {
    __shared__ int cur[E_EXPERTS];
    if (threadIdx.x < E_EXPERTS) cur[threadIdx.x] = 0;
    __syncthreads();
    int t = blockIdx.x * 256 + threadIdx.x;
#pragma unroll
    for (int sl = 0; sl < 2; sl++) {
        int ee = top_idx[2 * t + sl];
        int p = atomicAdd(&cur[ee], 1);
        int s = base[blockIdx.x * E_EXPERTS + ee] + p;
        perm[s] = t;
        wgt[s] = top_w[2 * t + sl];
        tok2slot[2 * t + sl] = s;
    }
}

// combine: out[t][d] = y[s0][d] + y[s1][d]  (nt accesses: y/out are stream-once)
__global__ void combine_kernel(const float* __restrict__ y, const int* __restrict__ tok2slot,
                               float* __restrict__ out) {
    int idx = blockIdx.x * blockDim.x + threadIdx.x;
    int stride = gridDim.x * blockDim.x;
    const int QR = D_DIM / 4;  // float4 per row
    for (int i = idx; i < N_TOK * QR; i += stride) {
        int t = i / QR, d4 = i - t * QR;
        int s0 = tok2slot[2 * t], s1 = tok2slot[2 * t + 1];
        f32x4 a = __builtin_nontemporal_load((const f32x4*)(y + (size_t)s0 * D_DIM) + d4);
        f32x4 b = __builtin_nontemporal_load((const f32x4*)(y + (size_t)s1 * D_DIM) + d4);
        f32x4 o = a + b;
        __builtin_nontemporal_store(o, (f32x4*)(out + (size_t)t * D_DIM) + d4);
    }
}

// ------- expert GEMMs: 128x256 tile, BK=32, TRI-buffered, 1 barrier/K-tile (T2+T4+T5) -------
// 512 threads = 8 waves (2M x 4N, 64x64 out each); LDS 72 KiB -> 2 blocks/CU (16 waves).
// Tri-buffer: stage(t+2) targets buf (t+2)%3 (never concurrently accessed) -> 1 barrier/K-tile.
// Per K-tile: stage 3 gloads (1 A + 2 B); 8 ds_read_b128; lgkm; 16 MFMA; vmcnt(3); barrier.
// Swizzle (both-sides, rule 21): row r granule g at phys pg=(g+(r>>1))&3; source pre-applies
// inverse, reads apply same map. Non-temporal stores keep the H/y streams out of L2.
// 1-D XCD-grouped grid: wgid = c + 8*(mb + MB_L*q); g = q*8+c -> (e = g/NB, nb = g%NB).
// MODE 0: A = xb gathered via perm, B = W1T[e], epilogue GELU -> Hout bf16 (nt)
// MODE 1: A = Hb contiguous,  B = W2T[e], epilogue weighted+bias -> Y f32 (nt, no atomics)
template <int MODE>
__global__ __launch_bounds__(512, 4) void moe_gemm_kernel(
    const ushort_t* __restrict__ A, const ushort_t* __restrict__ BT,
    const float* __restrict__ bias, const int* __restrict__ offsets,
    const int* __restrict__ counts, const int* __restrict__ perm,
    const float* __restrict__ wgt, ushort_t* __restrict__ Hout, float* __restrict__ Y) {
    constexpr int K = (MODE == 0) ? D_DIM : H_DIM;
    constexpr int N = (MODE == 0) ? H_DIM : D_DIM;
    constexpr int KT = K / 32;
    constexpr int NB = N / 256;

    const int wgid = blockIdx.x;
    const int c = wgid & 7;
    const int r = wgid >> 3;
    const int mb = r % MB_L;
    const int q = r / MB_L;
    const int g = q * 8 + c;
    const int e = g / NB;
    const int nb = g % NB;

    const int ne = counts[e];
    const int m0 = mb * 128;
    if (m0 >= ne) return;
    const int n0 = nb * 256;
    const int base = offsets[e];
    const ushort_t* Bt = BT + (size_t)e * ((size_t)N * K);

    __shared__ alignas(16) ushort_t As[3 * 128 * 32];   // 24 KB
    __shared__ alignas(16) ushort_t Bs[3 * 256 * 32];   // 48 KB

    const int tid = threadIdx.x;
    const int lane = tid & 63;
    const int w = tid >> 6;
    const int wm = w >> 2, wn = w & 3;           // 2 x 4 wave grid
    const int lr = lane & 15;
    const int gq = lane >> 4;                    // k-granule 0..3 (8 bf16 each)

    // staging: seg = 16 rows (1 KB). A: seg w (8 segs). B: segs 2w, 2w+1 (16 segs).
    // lane l of seg s: row = s*16 + (l>>2), phys granule = l&3, logical lg = ((l&3)-(row>>1))&3
    const int lrow = lane >> 2;
    const int lpg = lane & 3;
    int a_src, b_src[2];
    {
        int rowA = w * 16 + lrow;
        int lgA = (lpg - (rowA >> 1)) & 3;
        int rcl = min(m0 + rowA, ne - 1);
        int arow = (MODE == 0) ? perm[base + rcl] : (base + rcl);
        a_src = arow * K + lgA * 8;
#pragma unroll
        for (int i = 0; i < 2; i++) {
            int s = 2 * w + i;
            int rowB = s * 16 + lrow;
            int lgB = (lpg - (rowB >> 1)) & 3;
            b_src[i] = (n0 + rowB) * K + lgB * 8;
        }
    }

    auto stage = [&](int tt, int bi) {
        gload_lds16(A + (size_t)a_src + (size_t)tt * 32, &As[bi * 4096 + w * 512]);
#pragma unroll
        for (int i = 0; i < 2; i++)
            gload_lds16(Bt + (size_t)b_src[i] + (size_t)tt * 32,
                        &Bs[bi * 8192 + (2 * w + i) * 512]);
    };

    f32x4 acc[4][4];
#pragma unroll
    for (int i = 0; i < 4; i++)
#pragma unroll
        for (int j = 0; j < 4; j++) acc[i][j] = (f32x4){0.f, 0.f, 0.f, 0.f};

    // prologue: stage t=0 and t=1; wait t=0 (t=1's 3 loads stay in flight)
    stage(0, 0);
    stage(1, 1);
    asm volatile("s_waitcnt vmcnt(3)" ::: "memory");
    __builtin_amdgcn_s_barrier();

    int cur = 0;
    for (int t = 0; t < KT; ++t) {
        int sb = cur + 2; if (sb >= 3) sb -= 3;
        if (t + 2 < KT) stage(t + 2, sb);
        // fragment reads from buf cur (swizzled: phys granule = (gq + (R>>1)) & 3)
        bf16x8 af[4], bfr[4];
#pragma unroll
        for (int f = 0; f < 4; f++) {
            int Ra = wm * 64 + f * 16 + lr;
            int Rb = wn * 64 + f * 16 + lr;
            af[f]  = *(const bf16x8*)&As[cur * 4096 + Ra * 32 + (((gq + (Ra >> 1)) & 3) << 3)];
            bfr[f] = *(const bf16x8*)&Bs[cur * 8192 + Rb * 32 + (((gq + (Rb >> 1)) & 3) << 3)];
        }
        asm volatile("s_waitcnt lgkmcnt(0)" ::: "memory");
        __builtin_amdgcn_s_setprio(1);
#pragma unroll
        for (int fm = 0; fm < 4; fm++)
#pragma unroll
            for (int fc = 0; fc < 4; fc++)
                acc[fm][fc] = __builtin_amdgcn_mfma_f32_16x16x32_bf16(
                    af[fm], bfr[fc], acc[fm][fc], 0, 0, 0);
        __builtin_amdgcn_s_setprio(0);
        if (t + 2 < KT) asm volatile("s_waitcnt vmcnt(3)" ::: "memory");
        else            asm volatile("s_waitcnt vmcnt(0)" ::: "memory");
        __builtin_amdgcn_s_barrier();
        cur = (cur == 2) ? 0 : cur + 1;
    }

    const int rg0 = gq * 4;
#pragma unroll
    for (int fr = 0; fr < 4; fr++) {
#pragma unroll
        for (int fc = 0; fc < 4; fc++) {
            int cn = n0 + wn * 64 + fc * 16 + lr;
            float bi = bias[e * N + cn];
            f32x4 v = acc[fr][fc];
#pragma unroll
            for (int rg = 0; rg < 4; rg++) {
                int rm = m0 + wm * 64 + fr * 16 + rg0 + rg;
                if (rm < ne) {
                    if (MODE == 0) {
                        float xv = v[rg] + bi;
                        // gelu(x) ~= x * sigmoid(2*0.7978845608*(x + 0.044715 x^3))
                        float u = xv * 1.5957691216f * __builtin_fmaf(0.044715f * xv, xv, 1.0f);
                        float gl = xv / (1.f + __expf(-u));
                        __builtin_nontemporal_store(
                            f2bf(gl), &Hout[(size_t)(base + rm) * H_DIM + cn]);
                    } else {
                        int s = base + rm;
                        float wv = wgt[s];
                        __builtin_nontemporal_store(
                            wv * (v[rg] + bi), &Y[(size_t)s * D_DIM + cn]);
                    }
                }
            }
        }
    }
}

// ---------------- launch ----------------

extern "C" void kernel_launch(void* const* d_in, const int* in_sizes, int n_in,
                              void* d_out, int out_size, void* d_ws, size_t ws_size,
                              hipStream_t stream) {
    const float* x  = (const float*)d_in[0];
    const float* Wg = (const float*)d_in[1];
    const float* bg = (const float*)d_in[2];
    const float* W1 = (const float*)d_in[3];
    const float* b1 = (const float*)d_in[4];
    const float* W2 = (const float*)d_in[5];
    const float* b2 = (const float*)d_in[6];
    float* out = (float*)d_out;

    char* p = (char*)d_ws;
    ushort_t* xb  = (ushort_t*)p; p += (size_t)N_TOK * D_DIM * 2;
    ushort_t* W1T = (ushort_t*)p; p += (size_t)E_EXPERTS * H_DIM * D_DIM * 2;
    ushort_t* W2T = (ushort_t*)p; p += (size_t)E_EXPERTS * D_DIM * H_DIM * 2;
    ushort_t* Hb  = (ushort_t*)p; p += (size_t)SLOTS * H_DIM * 2;
    int*   top_idx = (int*)p;   p += (size_t)N_TOK * 2 * 4;
    float* top_w   = (float*)p; p += (size_t)N_TOK * 2 * 4;
    int*   perm    = (int*)p;   p += (size_t)SLOTS * 4;
    float* wgt     = (float*)p; p += (size_t)SLOTS * 4;
    int*   t2s     = (int*)p;   p += (size_t)SLOTS * 4;
    int*   bc      = (int*)p;   p += SCAT_BLOCKS * E_EXPERTS * 4;
    int*   basep   = (int*)p;   p += SCAT_BLOCKS * E_EXPERTS * 4;
    int*   counts  = (int*)p;   p += 64;
    int*   offsets = (int*)p;   p += 64;
    // y aliases xb+W1T (dead by GEMM2): 50.3 MB < 62.9 MB
    float* y = (float*)d_ws;

    gate_kernel<<<N_TOK / 4, 256, 0, stream>>>(x, Wg, bg, xb, top_idx, top_w);
    transpose_conv_kernel<<<dim3(H_DIM / 64, D_DIM / 64, E_EXPERTS), 256, 0, stream>>>(W1, W1T, D_DIM, H_DIM);
    transpose_conv_kernel<<<dim3(D_DIM / 64, H_DIM / 64, E_EXPERTS), 256, 0, stream>>>(W2, W2T, H_DIM, D_DIM);
    hist_kernel<<<SCAT_BLOCKS, 256, 0, stream>>>(top_idx, bc);
    scan_kernel<<<1, 64, 0, stream>>>(bc, counts, offsets, basep);
    scatter_kernel<<<SCAT_BLOCKS, 256, 0, stream>>>(top_idx, top_w, basep, perm, wgt, t2s);
    moe_gemm_kernel<0><<<8 * MB_L * (H_DIM / 256), 512, 0, stream>>>(
        xb, W1T, b1, offsets, counts, perm, wgt, Hb, nullptr);
    moe_gemm_kernel<1><<<8 * MB_L * (D_DIM / 256), 512, 0, stream>>>(
        Hb, W2T, b2, offsets, counts, perm, wgt, nullptr, y);
    combine_kernel<<<2048, 256, 0, stream>>>(y, t2s, out);
}

// Round 10
// 337.300 us; speedup vs baseline: 1.1722x; 1.1229x over previous
//
#include <hip/hip_runtime.h>
#include <hip/hip_bf16.h>
#include <math.h>

#define E_EXPERTS 8
#define D_DIM 768
#define H_DIM 3072
#define N_TOK 8192          // B*T = 4*2048
#define SLOTS (2 * N_TOK)
#define SCAT_BLOCKS 32      // hist/scatter blocks (256 tokens each)
#define MB_L 20             // launched m-blocks per group (covers ne <= 2560)

typedef unsigned short ushort_t;
typedef __attribute__((ext_vector_type(8))) __bf16 bf16x8;
typedef __attribute__((ext_vector_type(4))) float f32x4;

__device__ __forceinline__ unsigned short f2bf(float f) {
    unsigned int u = __float_as_uint(f);
    unsigned int r = (u + 0x7FFFu + ((u >> 16) & 1u)) >> 16;
    return (unsigned short)r;
}

// async 16B global -> LDS (wave-uniform LDS base + lane*16; global addr per-lane)
__device__ __forceinline__ void gload_lds16(const void* g, void* l) {
    __builtin_amdgcn_global_load_lds(
        (const __attribute__((address_space(1))) unsigned int*)g,
        (__attribute__((address_space(3))) unsigned int*)l, 16, 0, 0);
}

// ---------------- prep kernels ----------------

// dst[e][c][r] = bf16(src[e][r][c]);  R,C multiples of 64
__global__ void transpose_conv_kernel(const float* __restrict__ src, ushort_t* __restrict__ dst,
                                      int R, int C) {
    __shared__ float tile[64][65];
    int e = blockIdx.z;
    const float* S = src + (size_t)e * R * C;
    ushort_t* Dp = dst + (size_t)e * R * C;
    int c0 = blockIdx.x * 64, r0 = blockIdx.y * 64;
    int tx = threadIdx.x & 15, ty = threadIdx.x >> 4;  // 16 x 16
#pragma unroll
    for (int p = 0; p < 4; p++) {
        float4 v = *(const float4*)&S[(size_t)(r0 + ty + 16 * p) * C + c0 + tx * 4];
        tile[ty + 16 * p][tx * 4 + 0] = v.x;
        tile[ty + 16 * p][tx * 4 + 1] = v.y;
        tile[ty + 16 * p][tx * 4 + 2] = v.z;
        tile[ty + 16 * p][tx * 4 + 3] = v.w;
    }
    __syncthreads();
#pragma unroll
    for (int p = 0; p < 4; p++) {
        int cc = ty + 16 * p;
        int rr = tx * 4;
        ushort4 o;
        o.x = f2bf(tile[rr + 0][cc]);
        o.y = f2bf(tile[rr + 1][cc]);
        o.z = f2bf(tile[rr + 2][cc]);
        o.w = f2bf(tile[rr + 3][cc]);
        *(ushort4*)&Dp[(size_t)(c0 + cc) * R + r0 + rr] = o;
    }
}

// ---------------- routing ----------------

__global__ void gate_kernel(const float* __restrict__ x, const float* __restrict__ Wg,
                            const float* __restrict__ bg, ushort_t* __restrict__ xb,
                            int* __restrict__ top_idx, float* __restrict__ top_w) {
    int w = threadIdx.x >> 6, lane = threadIdx.x & 63;
    int t = blockIdx.x * 4 + w;
    if (t >= N_TOK) return;
    const float* xr = x + (size_t)t * D_DIM;
    float xs[12];
#pragma unroll
    for (int j = 0; j < 12; j++) xs[j] = xr[lane + 64 * j];
#pragma unroll
    for (int j = 0; j < 12; j++) xb[(size_t)t * D_DIM + lane + 64 * j] = f2bf(xs[j]);
    float pr[8];
#pragma unroll
    for (int ee = 0; ee < 8; ee++) {
        const float* wr = Wg + ee * D_DIM;
        float p = 0.f;
#pragma unroll
        for (int j = 0; j < 12; j++) p += xs[j] * wr[lane + 64 * j];
#pragma unroll
        for (int o = 32; o > 0; o >>= 1) p += __shfl_xor(p, o);
        pr[ee] = p + bg[ee];
    }
    float mx = pr[0];
#pragma unroll
    for (int ee = 1; ee < 8; ee++) mx = fmaxf(mx, pr[ee]);
    float s = 0.f;
#pragma unroll
    for (int ee = 0; ee < 8; ee++) { pr[ee] = expf(pr[ee] - mx); s += pr[ee]; }
    float inv = 1.f / s;
#pragma unroll
    for (int ee = 0; ee < 8; ee++) pr[ee] *= inv;
    int i0 = 0;
#pragma unroll
    for (int ee = 1; ee < 8; ee++) if (pr[ee] > pr[i0]) i0 = ee;
    int i1 = -1;
#pragma unroll
    for (int ee = 0; ee < 8; ee++) {
        if (ee == i0) continue;
        if (i1 < 0 || pr[ee] > pr[i1]) i1 = ee;
    }
    if (lane == 0) {
        top_idx[2 * t] = i0;
        top_idx[2 * t + 1] = i1;
        top_w[2 * t] = pr[i0];
        top_w[2 * t + 1] = pr[i1];
    }
}

__global__ void hist_kernel(const int* __restrict__ top_idx, int* __restrict__ bc) {
    __shared__ int h[E_EXPERTS];
    if (threadIdx.x < E_EXPERTS) h[threadIdx.x] = 0;
    __syncthreads();
    int t = blockIdx.x * 256 + threadIdx.x;
    atomicAdd(&h[top_idx[2 * t]], 1);
    atomicAdd(&h[top_idx[2 * t + 1]], 1);
    __syncthreads();
    if (threadIdx.x < E_EXPERTS) bc[blockIdx.x * E_EXPERTS + threadIdx.x] = h[threadIdx.x];
}

__global__ void scan_kernel(const int* __restrict__ bc, int* __restrict__ counts,
                            int* __restrict__ offsets, int* __restrict__ base) {
    int tid = threadIdx.x;
    if (tid < E_EXPERTS) {
        int acc = 0;
        for (int b = 0; b < SCAT_BLOCKS; b++) {
            base[b * E_EXPERTS + tid] = acc;
            acc += bc[b * E_EXPERTS + tid];
        }
        counts[tid] = acc;
    }
    __syncthreads();
    if (tid == 0) {
        int acc = 0;
        for (int e = 0; e < E_EXPERTS; e++) { offsets[e] = acc; acc += counts[e]; }
    }
    __syncthreads();
    if (tid < E_EXPERTS) {
        int o = offsets[tid];
        for (int b = 0; b < SCAT_BLOCKS; b++) base[b * E_EXPERTS + tid] += o;
    }
}

__global__ void scatter_kernel(const int* __restrict__ top_idx, const float* __restrict__ top_w,
                               const int* __restrict__ base, int* __restrict__ perm,
                               float* __restrict__ wgt, int* __restrict__ tok2slot) {
    __shared__ int cur[E_EXPERTS];
    if (threadIdx.x < E_EXPERTS) cur[threadIdx.x] = 0;
    __syncthreads();
    int t = blockIdx.x * 256 + threadIdx.x;
#pragma unroll
    for (int sl = 0; sl < 2; sl++) {
        int ee = top_idx[2 * t + sl];
        int p = atomicAdd(&cur[ee], 1);
        int s = base[blockIdx.x * E_EXPERTS + ee] + p;
        perm[s] = t;
        wgt[s] = top_w[2 * t + sl];
        tok2slot[2 * t + sl] = s;
    }
}

// combine: out[t][d] = y[s0][d] + y[s1][d]  (nt on the stream-once accesses)
__global__ void combine_kernel(const float* __restrict__ y, const int* __restrict__ tok2slot,
                               float* __restrict__ out) {
    int idx = blockIdx.x * blockDim.x + threadIdx.x;
    int stride = gridDim.x * blockDim.x;
    const int QR = D_DIM / 4;  // float4 per row
    for (int i = idx; i < N_TOK * QR; i += stride) {
        int t = i / QR, d4 = i - t * QR;
        int s0 = tok2slot[2 * t], s1 = tok2slot[2 * t + 1];
        f32x4 a = __builtin_nontemporal_load((const f32x4*)(y + (size_t)s0 * D_DIM) + d4);
        f32x4 b = __builtin_nontemporal_load((const f32x4*)(y + (size_t)s1 * D_DIM) + d4);
        f32x4 o = a + b;
        __builtin_nontemporal_store(o, (f32x4*)(out + (size_t)t * D_DIM) + d4);
    }
}

// ------- expert GEMMs: m97-faithful 128x128, BK=64, SINGLE-buffer, 32 KiB LDS -------
// 256 threads = 4 waves (2M x 2N, 64x64 out each); 32 KiB LDS -> 3-4 blocks/CU.
// Per K-tile: __syncthreads (compiler drains vmcnt -> publishes tile t); 16 ds_read_b128
// (compiler fine-grained lgkm waits, m97); 32 MFMA; __syncthreads; stage t+1 (8 gloads).
// Per-tile drain latency covered by co-resident blocks (m114) -- no asm waitcnt, no setprio.
// Staging (round-6 verified): chunk = i*256+tid; row = chunk>>3; granule XOR (row&7) ->
// each instruction's 64 lanes cover 8 FULL 128B lines (union-coalesced); LDS dest linear.
// Read side applies same XOR: granule = (kk*4 + (lane>>4)) ^ (lr&7). Conflicts == 0 (r6).
// 1-D XCD-grouped grid: wgid = c + 8*(mb + MB_L*q); g = q*8+c -> (e = g/NB, nb = g%NB):
// all live mb-blocks of one (e,nb) share an XCD -> B panel L2-resident.
// MODE 0: A = xb gathered via perm, B = W1T[e], epilogue GELU -> Hout bf16
// MODE 1: A = Hb contiguous,  B = W2T[e], epilogue weighted+bias -> Y f32 (no atomics)
template <int MODE>
__global__ __launch_bounds__(256, 3) void moe_gemm_kernel(
    const ushort_t* __restrict__ A, const ushort_t* __restrict__ BT,
    const float* __restrict__ bias, const int* __restrict__ offsets,
    const int* __restrict__ counts, const int* __restrict__ perm,
    const float* __restrict__ wgt, ushort_t* __restrict__ Hout, float* __restrict__ Y) {
    constexpr int K = (MODE == 0) ? D_DIM : H_DIM;
    constexpr int N = (MODE == 0) ? H_DIM : D_DIM;
    constexpr int KT = K / 64;
    constexpr int NB = N / 128;

    const int wgid = blockIdx.x;
    const int c = wgid & 7;
    const int r = wgid >> 3;
    const int mb = r % MB_L;
    const int q = r / MB_L;
    const int g = q * 8 + c;
    const int e = g / NB;
    const int nb = g % NB;

    const int ne = counts[e];
    const int m0 = mb * 128;
    if (m0 >= ne) return;
    const int n0 = nb * 128;
    const int base = offsets[e];
    const ushort_t* Bt = BT + (size_t)e * ((size_t)N * K);

    __shared__ alignas(16) ushort_t As[128 * 64];   // 16 KB
    __shared__ alignas(16) ushort_t Bs[128 * 64];   // 16 KB

    const int tid = threadIdx.x;
    const int lane = tid & 63;
    const int w = tid >> 6;
    const int wm = w >> 1, wn = w & 1;           // 2 x 2 wave grid
    const int lr = lane & 15;
    const int lk8 = lane >> 4;                   // base k-granule 0..3

    // staging: chunk = i*256 + tid (i=0..3); row = chunk>>3 = i*32 + (tid>>3); granule = tid&7.
    // source granule pre-swizzled: (tid&7) ^ (row&7); row&7 == (tid>>3)&7 (i*32 multiple of 8).
    const int trow = tid >> 3;                   // 0..31
    const int sg8 = (((tid & 7) ^ (trow & 7)) * 8);
    int a_off[4], b_off[4];
#pragma unroll
    for (int i = 0; i < 4; i++) {
        int row = i * 32 + trow;
        int rcl = min(m0 + row, ne - 1);
        int arow = (MODE == 0) ? perm[base + rcl] : (base + rcl);
        a_off[i] = arow * K + sg8;
        b_off[i] = (n0 + row) * K + sg8;
    }

    auto stage = [&](int tt) {
#pragma unroll
        for (int i = 0; i < 4; i++)
            gload_lds16(A + (size_t)a_off[i] + (size_t)tt * 64, &As[(i * 256 + w * 64) * 8]);
#pragma unroll
        for (int i = 0; i < 4; i++)
            gload_lds16(Bt + (size_t)b_off[i] + (size_t)tt * 64, &Bs[(i * 256 + w * 64) * 8]);
    };

    f32x4 acc[4][4];
#pragma unroll
    for (int i = 0; i < 4; i++)
#pragma unroll
        for (int j = 0; j < 4; j++) acc[i][j] = (f32x4){0.f, 0.f, 0.f, 0.f};

    // swizzled read column offsets (elements): granule = (kk*4 + lk8) ^ (lr&7)
    const int cg0 = ((0 * 4 + lk8) ^ (lr & 7)) << 3;
    const int cg1 = ((1 * 4 + lk8) ^ (lr & 7)) << 3;

    stage(0);
    for (int t = 0; t < KT; ++t) {
        __syncthreads();                         // drains staging -> tile t visible
        bf16x8 bfr[4][2];
#pragma unroll
        for (int fc = 0; fc < 4; fc++) {
            int Rb = (wn * 64 + fc * 16 + lr) * 64;
            bfr[fc][0] = *(const bf16x8*)&Bs[Rb + cg0];
            bfr[fc][1] = *(const bf16x8*)&Bs[Rb + cg1];
        }
#pragma unroll
        for (int pl = 0; pl < 4; pl++) {
            int Ra = (wm * 64 + pl * 16 + lr) * 64;
            bf16x8 a0 = *(const bf16x8*)&As[Ra + cg0];
            bf16x8 a1 = *(const bf16x8*)&As[Ra + cg1];
#pragma unroll
            for (int fc = 0; fc < 4; fc++) {
                acc[pl][fc] = __builtin_amdgcn_mfma_f32_16x16x32_bf16(a0, bfr[fc][0], acc[pl][fc], 0, 0, 0);
                acc[pl][fc] = __builtin_amdgcn_mfma_f32_16x16x32_bf16(a1, bfr[fc][1], acc[pl][fc], 0, 0, 0);
            }
        }
        __syncthreads();                         // all waves done reading tile t
        if (t + 1 < KT) stage(t + 1);            // overwrite buffer with tile t+1
    }

    const int rg0 = lk8 * 4;
#pragma unroll
    for (int fr = 0; fr < 4; fr++) {
#pragma unroll
        for (int fc = 0; fc < 4; fc++) {
            int cn = n0 + wn * 64 + fc * 16 + lr;
            float bi = bias[e * N + cn];
            f32x4 v = acc[fr][fc];
#pragma unroll
            for (int rg = 0; rg < 4; rg++) {
                int rm = m0 + wm * 64 + fr * 16 + rg0 + rg;
                if (rm < ne) {
                    if (MODE == 0) {
                        float xv = v[rg] + bi;
                        // gelu(x) ~= x * sigmoid(2*0.7978845608*(x + 0.044715 x^3))
                        float u = xv * 1.5957691216f * __builtin_fmaf(0.044715f * xv, xv, 1.0f);
                        float gl = xv / (1.f + __expf(-u));
                        Hout[(size_t)(base + rm) * H_DIM + cn] = f2bf(gl);
                    } else {
                        int s = base + rm;
                        float wv = wgt[s];
                        Y[(size_t)s * D_DIM + cn] = wv * (v[rg] + bi);
                    }
                }
            }
        }
    }
}

// ---------------- launch ----------------

extern "C" void kernel_launch(void* const* d_in, const int* in_sizes, int n_in,
                              void* d_out, int out_size, void* d_ws, size_t ws_size,
                              hipStream_t stream) {
    const float* x  = (const float*)d_in[0];
    const float* Wg = (const float*)d_in[1];
    const float* bg = (const float*)d_in[2];
    const float* W1 = (const float*)d_in[3];
    const float* b1 = (const float*)d_in[4];
    const float* W2 = (const float*)d_in[5];
    const float* b2 = (const float*)d_in[6];
    float* out = (float*)d_out;

    char* p = (char*)d_ws;
    ushort_t* xb  = (ushort_t*)p; p += (size_t)N_TOK * D_DIM * 2;
    ushort_t* W1T = (ushort_t*)p; p += (size_t)E_EXPERTS * H_DIM * D_DIM * 2;
    ushort_t* W2T = (ushort_t*)p; p += (size_t)E_EXPERTS * D_DIM * H_DIM * 2;
    ushort_t* Hb  = (ushort_t*)p; p += (size_t)SLOTS * H_DIM * 2;
    int*   top_idx = (int*)p;   p += (size_t)N_TOK * 2 * 4;
    float* top_w   = (float*)p; p += (size_t)N_TOK * 2 * 4;
    int*   perm    = (int*)p;   p += (size_t)SLOTS * 4;
    float* wgt     = (float*)p; p += (size_t)SLOTS * 4;
    int*   t2s     = (int*)p;   p += (size_t)SLOTS * 4;
    int*   bc      = (int*)p;   p += SCAT_BLOCKS * E_EXPERTS * 4;
    int*   basep   = (int*)p;   p += SCAT_BLOCKS * E_EXPERTS * 4;
    int*   counts  = (int*)p;   p += 64;
    int*   offsets = (int*)p;   p += 64;
    // y aliases xb+W1T (dead by GEMM2): 50.3 MB < 62.9 MB
    float* y = (float*)d_ws;

    gate_kernel<<<N_TOK / 4, 256, 0, stream>>>(x, Wg, bg, xb, top_idx, top_w);
    transpose_conv_kernel<<<dim3(H_DIM / 64, D_DIM / 64, E_EXPERTS), 256, 0, stream>>>(W1, W1T, D_DIM, H_DIM);
    transpose_conv_kernel<<<dim3(D_DIM / 64, H_DIM / 64, E_EXPERTS), 256, 0, stream>>>(W2, W2T, H_DIM, D_DIM);
    hist_kernel<<<SCAT_BLOCKS, 256, 0, stream>>>(top_idx, bc);
    scan_kernel<<<1, 64, 0, stream>>>(bc, counts, offsets, basep);
    scatter_kernel<<<SCAT_BLOCKS, 256, 0, stream>>>(top_idx, top_w, basep, perm, wgt, t2s);
    moe_gemm_kernel<0><<<8 * MB_L * (H_DIM / 128), 256, 0, stream>>>(
        xb, W1T, b1, offsets, counts, perm, wgt, Hb, nullptr);
    moe_gemm_kernel<1><<<8 * MB_L * (D_DIM / 128), 256, 0, stream>>>(
        Hb, W2T, b2, offsets, counts, perm, wgt, nullptr, y);
    combine_kernel<<<2048, 256, 0, stream>>>(y, t2s, out);
}

// Round 11
// 327.117 us; speedup vs baseline: 1.2087x; 1.0311x over previous
//
#include <hip/hip_runtime.h>
#include <hip/hip_bf16.h>
#include <math.h>

#define E_EXPERTS 8
#define D_DIM 768
#define H_DIM 3072
#define N_TOK 8192          // B*T = 4*2048
#define SLOTS (2 * N_TOK)
#define SCAT_BLOCKS 32      // hist/scatter blocks (256 tokens each)
#define MB_L 20             // launched m-blocks per group (covers ne <= 2560)

typedef unsigned short ushort_t;
typedef __attribute__((ext_vector_type(8))) __bf16 bf16x8;
typedef __attribute__((ext_vector_type(4))) float f32x4;

__device__ __forceinline__ unsigned short f2bf(float f) {
    unsigned int u = __float_as_uint(f);
    unsigned int r = (u + 0x7FFFu + ((u >> 16) & 1u)) >> 16;
    return (unsigned short)r;
}

// async 16B global -> LDS (wave-uniform LDS base + lane*16; global addr per-lane)
__device__ __forceinline__ void gload_lds16(const void* g, void* l) {
    __builtin_amdgcn_global_load_lds(
        (const __attribute__((address_space(1))) unsigned int*)g,
        (__attribute__((address_space(3))) unsigned int*)l, 16, 0, 0);
}

// ---------------- prep kernels ----------------

// dst[e][c][r] = bf16(src[e][r][c]);  R,C multiples of 64
__global__ void transpose_conv_kernel(const float* __restrict__ src, ushort_t* __restrict__ dst,
                                      int R, int C) {
    __shared__ float tile[64][65];
    int e = blockIdx.z;
    const float* S = src + (size_t)e * R * C;
    ushort_t* Dp = dst + (size_t)e * R * C;
    int c0 = blockIdx.x * 64, r0 = blockIdx.y * 64;
    int tx = threadIdx.x & 15, ty = threadIdx.x >> 4;  // 16 x 16
#pragma unroll
    for (int p = 0; p < 4; p++) {
        float4 v = *(const float4*)&S[(size_t)(r0 + ty + 16 * p) * C + c0 + tx * 4];
        tile[ty + 16 * p][tx * 4 + 0] = v.x;
        tile[ty + 16 * p][tx * 4 + 1] = v.y;
        tile[ty + 16 * p][tx * 4 + 2] = v.z;
        tile[ty + 16 * p][tx * 4 + 3] = v.w;
    }
    __syncthreads();
#pragma unroll
    for (int p = 0; p < 4; p++) {
        int cc = ty + 16 * p;
        int rr = tx * 4;
        ushort4 o;
        o.x = f2bf(tile[rr + 0][cc]);
        o.y = f2bf(tile[rr + 1][cc]);
        o.z = f2bf(tile[rr + 2][cc]);
        o.w = f2bf(tile[rr + 3][cc]);
        *(ushort4*)&Dp[(size_t)(c0 + cc) * R + r0 + rr] = o;
    }
}

// ---------------- routing ----------------

__global__ void gate_kernel(const float* __restrict__ x, const float* __restrict__ Wg,
                            const float* __restrict__ bg, ushort_t* __restrict__ xb,
                            int* __restrict__ top_idx, float* __restrict__ top_w) {
    int w = threadIdx.x >> 6, lane = threadIdx.x & 63;
    int t = blockIdx.x * 4 + w;
    if (t >= N_TOK) return;
    const float* xr = x + (size_t)t * D_DIM;
    float xs[12];
#pragma unroll
    for (int j = 0; j < 12; j++) xs[j] = xr[lane + 64 * j];
#pragma unroll
    for (int j = 0; j < 12; j++) xb[(size_t)t * D_DIM + lane + 64 * j] = f2bf(xs[j]);
    float pr[8];
#pragma unroll
    for (int ee = 0; ee < 8; ee++) {
        const float* wr = Wg + ee * D_DIM;
        float p = 0.f;
#pragma unroll
        for (int j = 0; j < 12; j++) p += xs[j] * wr[lane + 64 * j];
#pragma unroll
        for (int o = 32; o > 0; o >>= 1) p += __shfl_xor(p, o);
        pr[ee] = p + bg[ee];
    }
    float mx = pr[0];
#pragma unroll
    for (int ee = 1; ee < 8; ee++) mx = fmaxf(mx, pr[ee]);
    float s = 0.f;
#pragma unroll
    for (int ee = 0; ee < 8; ee++) { pr[ee] = expf(pr[ee] - mx); s += pr[ee]; }
    float inv = 1.f / s;
#pragma unroll
    for (int ee = 0; ee < 8; ee++) pr[ee] *= inv;
    int i0 = 0;
#pragma unroll
    for (int ee = 1; ee < 8; ee++) if (pr[ee] > pr[i0]) i0 = ee;
    int i1 = -1;
#pragma unroll
    for (int ee = 0; ee < 8; ee++) {
        if (ee == i0) continue;
        if (i1 < 0 || pr[ee] > pr[i1]) i1 = ee;
    }
    if (lane == 0) {
        top_idx[2 * t] = i0;
        top_idx[2 * t + 1] = i1;
        top_w[2 * t] = pr[i0];
        top_w[2 * t + 1] = pr[i1];
    }
}

__global__ void hist_kernel(const int* __restrict__ top_idx, int* __restrict__ bc) {
    __shared__ int h[E_EXPERTS];
    if (threadIdx.x < E_EXPERTS) h[threadIdx.x] = 0;
    __syncthreads();
    int t = blockIdx.x * 256 + threadIdx.x;
    atomicAdd(&h[top_idx[2 * t]], 1);
    atomicAdd(&h[top_idx[2 * t + 1]], 1);
    __syncthreads();
    if (threadIdx.x < E_EXPERTS) bc[blockIdx.x * E_EXPERTS + threadIdx.x] = h[threadIdx.x];
}

__global__ void scan_kernel(const int* __restrict__ bc, int* __restrict__ counts,
                            int* __restrict__ offsets, int* __restrict__ base) {
    int tid = threadIdx.x;
    if (tid < E_EXPERTS) {
        int acc = 0;
        for (int b = 0; b < SCAT_BLOCKS; b++) {
            base[b * E_EXPERTS + tid] = acc;
            acc += bc[b * E_EXPERTS + tid];
        }
        counts[tid] = acc;
    }
    __syncthreads();
    if (tid == 0) {
        int acc = 0;
        for (int e = 0; e < E_EXPERTS; e++) { offsets[e] = acc; acc += counts[e]; }
    }
    __syncthreads();
    if (tid < E_EXPERTS) {
        int o = offsets[tid];
        for (int b = 0; b < SCAT_BLOCKS; b++) base[b * E_EXPERTS + tid] += o;
    }
}

__global__ void scatter_kernel(const int* __restrict__ top_idx, const float* __restrict__ top_w,
                               const int* __restrict__ base, int* __restrict__ perm,
                               float* __restrict__ wgt, int* __restrict__ tok2slot) {
    __shared__ int cur[E_EXPERTS];
    if (threadIdx.x < E_EXPERTS) cur[threadIdx.x] = 0;
    __syncthreads();
    int t = blockIdx.x * 256 + threadIdx.x;
#pragma unroll
    for (int sl = 0; sl < 2; sl++) {
        int ee = top_idx[2 * t + sl];
        int p = atomicAdd(&cur[ee], 1);
        int s = base[blockIdx.x * E_EXPERTS + ee] + p;
        perm[s] = t;
        wgt[s] = top_w[2 * t + sl];
        tok2slot[2 * t + sl] = s;
    }
}

// combine: out[t][d] = y[s0][d] + y[s1][d]  (nt on the stream-once accesses)
__global__ void combine_kernel(const float* __restrict__ y, const int* __restrict__ tok2slot,
                               float* __restrict__ out) {
    int idx = blockIdx.x * blockDim.x + threadIdx.x;
    int stride = gridDim.x * blockDim.x;
    const int QR = D_DIM / 4;  // float4 per row
    for (int i = idx; i < N_TOK * QR; i += stride) {
        int t = i / QR, d4 = i - t * QR;
        int s0 = tok2slot[2 * t], s1 = tok2slot[2 * t + 1];
        f32x4 a = __builtin_nontemporal_load((const f32x4*)(y + (size_t)s0 * D_DIM) + d4);
        f32x4 b = __builtin_nontemporal_load((const f32x4*)(y + (size_t)s1 * D_DIM) + d4);
        f32x4 o = a + b;
        __builtin_nontemporal_store(o, (f32x4*)(out + (size_t)t * D_DIM) + d4);
    }
}

// ------- expert GEMMs: 128x128, BK=64, single-buffer + in-block overlap, 4 blocks/CU -------
// 256 threads = 4 waves (2M x 2N, 64x64 out each); 32 KiB LDS, __launch_bounds__(256,4).
// Per K-tile: __syncthreads (vm-drain -> tile t visible); 16 ds_read_b128;
// __syncthreads (lgkm-drain -> all reads in regs, buffer FREE); stage(t+1) (async, 8 gloads);
// 32 MFMA (register-only, OVERLAPS staging). Cross-block coverage on top (m114).
// Staging swizzle (round-6 verified): source granule (tid&7)^(row&7), LDS dest linear;
// reads apply same XOR -> conflicts 0; each gload's 64 lanes cover 8 full 128B lines.
// 1-D XCD-grouped grid: wgid = c + 8*(mb + MB_L*q); g = q*8+c -> (e = g/NB, nb = g%NB).
// MODE 0: A = xb gathered via perm, B = W1T[e], epilogue GELU -> Hout bf16
// MODE 1: A = Hb contiguous,  B = W2T[e], epilogue weighted+bias -> Y f32 (no atomics)
template <int MODE>
__global__ __launch_bounds__(256, 4) void moe_gemm_kernel(
    const ushort_t* __restrict__ A, const ushort_t* __restrict__ BT,
    const float* __restrict__ bias, const int* __restrict__ offsets,
    const int* __restrict__ counts, const int* __restrict__ perm,
    const float* __restrict__ wgt, ushort_t* __restrict__ Hout, float* __restrict__ Y) {
    constexpr int K = (MODE == 0) ? D_DIM : H_DIM;
    constexpr int N = (MODE == 0) ? H_DIM : D_DIM;
    constexpr int KT = K / 64;
    constexpr int NB = N / 128;

    const int wgid = blockIdx.x;
    const int c = wgid & 7;
    const int r = wgid >> 3;
    const int mb = r % MB_L;
    const int q = r / MB_L;
    const int g = q * 8 + c;
    const int e = g / NB;
    const int nb = g % NB;

    const int ne = counts[e];
    const int m0 = mb * 128;
    if (m0 >= ne) return;
    const int n0 = nb * 128;
    const int base = offsets[e];
    const ushort_t* Bt = BT + (size_t)e * ((size_t)N * K);

    __shared__ alignas(16) ushort_t As[128 * 64];   // 16 KB
    __shared__ alignas(16) ushort_t Bs[128 * 64];   // 16 KB

    const int tid = threadIdx.x;
    const int lane = tid & 63;
    const int w = tid >> 6;
    const int wm = w >> 1, wn = w & 1;           // 2 x 2 wave grid
    const int lr = lane & 15;
    const int lk8 = lane >> 4;                   // base k-granule 0..3

    // staging: chunk = i*256 + tid (i=0..3); row = i*32 + (tid>>3); granule = tid&7.
    // source granule pre-swizzled: (tid&7) ^ (row&7); row&7 == (tid>>3)&7.
    const int trow = tid >> 3;                   // 0..31
    const int sg8 = (((tid & 7) ^ (trow & 7)) * 8);
    int a_off[4], b_off[4];
#pragma unroll
    for (int i = 0; i < 4; i++) {
        int row = i * 32 + trow;
        int rcl = min(m0 + row, ne - 1);
        int arow = (MODE == 0) ? perm[base + rcl] : (base + rcl);
        a_off[i] = arow * K + sg8;
        b_off[i] = (n0 + row) * K + sg8;
    }

    auto stage = [&](int tt) {
#pragma unroll
        for (int i = 0; i < 4; i++)
            gload_lds16(A + (size_t)a_off[i] + (size_t)tt * 64, &As[(i * 256 + w * 64) * 8]);
#pragma unroll
        for (int i = 0; i < 4; i++)
            gload_lds16(Bt + (size_t)b_off[i] + (size_t)tt * 64, &Bs[(i * 256 + w * 64) * 8]);
    };

    f32x4 acc[4][4];
#pragma unroll
    for (int i = 0; i < 4; i++)
#pragma unroll
        for (int j = 0; j < 4; j++) acc[i][j] = (f32x4){0.f, 0.f, 0.f, 0.f};

    // swizzled read column offsets (elements): granule = (kk*4 + lk8) ^ (lr&7)
    const int cg0 = ((0 * 4 + lk8) ^ (lr & 7)) << 3;
    const int cg1 = ((1 * 4 + lk8) ^ (lr & 7)) << 3;

    stage(0);
    for (int t = 0; t < KT; ++t) {
        __syncthreads();                         // vm-drain: tile t visible in LDS
        bf16x8 bfr[4][2], afr[4][2];
#pragma unroll
        for (int fc = 0; fc < 4; fc++) {
            int Rb = (wn * 64 + fc * 16 + lr) * 64;
            bfr[fc][0] = *(const bf16x8*)&Bs[Rb + cg0];
            bfr[fc][1] = *(const bf16x8*)&Bs[Rb + cg1];
        }
#pragma unroll
        for (int pl = 0; pl < 4; pl++) {
            int Ra = (wm * 64 + pl * 16 + lr) * 64;
            afr[pl][0] = *(const bf16x8*)&As[Ra + cg0];
            afr[pl][1] = *(const bf16x8*)&As[Ra + cg1];
        }
        __syncthreads();                         // lgkm-drain: reads in regs, buffer free
        if (t + 1 < KT) stage(t + 1);            // async loads overlap the MFMA below
#pragma unroll
        for (int pl = 0; pl < 4; pl++)
#pragma unroll
            for (int fc = 0; fc < 4; fc++) {
                acc[pl][fc] = __builtin_amdgcn_mfma_f32_16x16x32_bf16(afr[pl][0], bfr[fc][0], acc[pl][fc], 0, 0, 0);
                acc[pl][fc] = __builtin_amdgcn_mfma_f32_16x16x32_bf16(afr[pl][1], bfr[fc][1], acc[pl][fc], 0, 0, 0);
            }
    }

    const int rg0 = lk8 * 4;
#pragma unroll
    for (int fr = 0; fr < 4; fr++) {
#pragma unroll
        for (int fc = 0; fc < 4; fc++) {
            int cn = n0 + wn * 64 + fc * 16 + lr;
            float bi = bias[e * N + cn];
            f32x4 v = acc[fr][fc];
#pragma unroll
            for (int rg = 0; rg < 4; rg++) {
                int rm = m0 + wm * 64 + fr * 16 + rg0 + rg;
                if (rm < ne) {
                    if (MODE == 0) {
                        float xv = v[rg] + bi;
                        // gelu(x) ~= x * sigmoid(2*0.7978845608*(x + 0.044715 x^3))
                        float u = xv * 1.5957691216f * __builtin_fmaf(0.044715f * xv, xv, 1.0f);
                        float gl = xv / (1.f + __expf(-u));
                        Hout[(size_t)(base + rm) * H_DIM + cn] = f2bf(gl);
                    } else {
                        int s = base + rm;
                        float wv = wgt[s];
                        Y[(size_t)s * D_DIM + cn] = wv * (v[rg] + bi);
                    }
                }
            }
        }
    }
}

// ---------------- launch ----------------

extern "C" void kernel_launch(void* const* d_in, const int* in_sizes, int n_in,
                              void* d_out, int out_size, void* d_ws, size_t ws_size,
                              hipStream_t stream) {
    const float* x  = (const float*)d_in[0];
    const float* Wg = (const float*)d_in[1];
    const float* bg = (const float*)d_in[2];
    const float* W1 = (const float*)d_in[3];
    const float* b1 = (const float*)d_in[4];
    const float* W2 = (const float*)d_in[5];
    const float* b2 = (const float*)d_in[6];
    float* out = (float*)d_out;

    char* p = (char*)d_ws;
    ushort_t* xb  = (ushort_t*)p; p += (size_t)N_TOK * D_DIM * 2;
    ushort_t* W1T = (ushort_t*)p; p += (size_t)E_EXPERTS * H_DIM * D_DIM * 2;
    ushort_t* W2T = (ushort_t*)p; p += (size_t)E_EXPERTS * D_DIM * H_DIM * 2;
    ushort_t* Hb  = (ushort_t*)p; p += (size_t)SLOTS * H_DIM * 2;
    int*   top_idx = (int*)p;   p += (size_t)N_TOK * 2 * 4;
    float* top_w   = (float*)p; p += (size_t)N_TOK * 2 * 4;
    int*   perm    = (int*)p;   p += (size_t)SLOTS * 4;
    float* wgt     = (float*)p; p += (size_t)SLOTS * 4;
    int*   t2s     = (int*)p;   p += (size_t)SLOTS * 4;
    int*   bc      = (int*)p;   p += SCAT_BLOCKS * E_EXPERTS * 4;
    int*   basep   = (int*)p;   p += SCAT_BLOCKS * E_EXPERTS * 4;
    int*   counts  = (int*)p;   p += 64;
    int*   offsets = (int*)p;   p += 64;
    // y aliases xb+W1T (dead by GEMM2): 50.3 MB < 62.9 MB
    float* y = (float*)d_ws;

    gate_kernel<<<N_TOK / 4, 256, 0, stream>>>(x, Wg, bg, xb, top_idx, top_w);
    transpose_conv_kernel<<<dim3(H_DIM / 64, D_DIM / 64, E_EXPERTS), 256, 0, stream>>>(W1, W1T, D_DIM, H_DIM);
    transpose_conv_kernel<<<dim3(D_DIM / 64, H_DIM / 64, E_EXPERTS), 256, 0, stream>>>(W2, W2T, H_DIM, D_DIM);
    hist_kernel<<<SCAT_BLOCKS, 256, 0, stream>>>(top_idx, bc);
    scan_kernel<<<1, 64, 0, stream>>>(bc, counts, offsets, basep);
    scatter_kernel<<<SCAT_BLOCKS, 256, 0, stream>>>(top_idx, top_w, basep, perm, wgt, t2s);
    moe_gemm_kernel<0><<<8 * MB_L * (H_DIM / 128), 256, 0, stream>>>(
        xb, W1T, b1, offsets, counts, perm, wgt, Hb, nullptr);
    moe_gemm_kernel<1><<<8 * MB_L * (D_DIM / 128), 256, 0, stream>>>(
        Hb, W2T, b2, offsets, counts, perm, wgt, nullptr, y);
    combine_kernel<<<2048, 256, 0, stream>>>(y, t2s, out);
}